// Round 5
// baseline (229.920 us; speedup 1.0000x reference)
//
#include <hip/hip_runtime.h>

#define IH 512
#define IW 512
#define OH 510
#define OW 510
#define NB 32
#define KO 16

typedef float f32x4 __attribute__((ext_vector_type(4)));
typedef float f32x2 __attribute__((ext_vector_type(2)));

// One block = one half-plane (n, o, h): 255 output rows, ONE contiguous
// ~0.5 MB write stream. 1024 blocks total -> ~1K write streams (vs 32K in
// R1) to avoid DRAM page thrash. bid mapping puts all 16 planes of image n
// on the same XCD (bid % 8 == n % 8) so x re-reads hit that XCD's 4MB L2.
// Output uses nontemporal stores to keep L2 reserved for x.
__global__ __launch_bounds__(256) void conv3x3_k16_kernel(
    const float* __restrict__ x,
    const float* __restrict__ k,
    float* __restrict__ out)
{
    // Decode bid = (n%8) + 8*(o + 16*h + 32*(n/8))
    const int bid = blockIdx.x;
    const int nlo = bid & 7;
    int rest = bid >> 3;          // o + 16*h + 32*(n/8)
    const int o   = rest & 15;
    rest >>= 4;                   // h + 2*(n/8)
    const int h   = rest & 1;
    const int nhi = rest >> 1;
    const int n   = nhi * 8 + nlo;

    const int t    = threadIdx.x;
    const int half = t >> 7;       // row within pair
    const int tt   = t & 127;
    const bool tail = (tt == 127);

    const int r0   = h * 255;      // first output row of this half
    const int rend = r0 + 254;     // last output row

    // 9 weights, thread-uniform -> SGPRs
    float w[9];
#pragma unroll
    for (int q = 0; q < 9; ++q) w[q] = k[o * 9 + q];

    const float* xn = x + (size_t)n * IH * IW;
    float* on = out + ((size_t)(n * KO + o) * OH) * OW;

#pragma unroll 1
    for (int it = 0; it < 128; ++it) {
        const int i = r0 + 2 * it + half;   // output row
        if (i > rend) break;                // only last iteration, half=1

        // Even i: full threads j=4tt (tail j=508); odd i: j=4tt+2 (tail j=0)
        int j;
        if ((i & 1) == 0) j = tail ? 508 : 4 * tt;
        else              j = tail ? 0   : 4 * tt + 2;

        const float* xr = xn + (size_t)i * IW + j;

        float xv[3][6];
#pragma unroll
        for (int rr = 0; rr < 3; ++rr) {
            const float2 a = *reinterpret_cast<const float2*>(xr + rr * IW);
            const float2 b = *reinterpret_cast<const float2*>(xr + rr * IW + 2);
            xv[rr][0] = a.x; xv[rr][1] = a.y; xv[rr][2] = b.x; xv[rr][3] = b.y;
            if (!tail) {
                const float2 c = *reinterpret_cast<const float2*>(xr + rr * IW + 4);
                xv[rr][4] = c.x; xv[rr][5] = c.y;
            } else {
                xv[rr][4] = 0.0f; xv[rr][5] = 0.0f;
            }
        }

        float acc0 = 0.0f, acc1 = 0.0f, acc2 = 0.0f, acc3 = 0.0f;
#pragma unroll
        for (int rr = 0; rr < 3; ++rr) {
#pragma unroll
            for (int c = 0; c < 3; ++c) {
                const float kv = w[rr * 3 + c];
                acc0 = fmaf(xv[rr][c],     kv, acc0);
                acc1 = fmaf(xv[rr][c + 1], kv, acc1);
                acc2 = fmaf(xv[rr][c + 2], kv, acc2);
                acc3 = fmaf(xv[rr][c + 3], kv, acc3);
            }
        }

        float* p = on + (size_t)i * OW + j;
        if (!tail) {
            f32x4 v; v.x = acc0; v.y = acc1; v.z = acc2; v.w = acc3;
            __builtin_nontemporal_store(v, reinterpret_cast<f32x4*>(p));
        } else {
            f32x2 v; v.x = acc0; v.y = acc1;
            __builtin_nontemporal_store(v, reinterpret_cast<f32x2*>(p));
        }
    }
}

extern "C" void kernel_launch(void* const* d_in, const int* in_sizes, int n_in,
                              void* d_out, int out_size, void* d_ws, size_t ws_size,
                              hipStream_t stream) {
    const float* x   = (const float*)d_in[0];
    const float* ker = (const float*)d_in[1];
    float* out       = (float*)d_out;

    dim3 grid(NB * KO * 2);   // 1024 blocks: (n, o, half-plane)
    dim3 block(256);
    conv3x3_k16_kernel<<<grid, block, 0, stream>>>(x, ker, out);
}

// Round 6
// 198.240 us; speedup vs baseline: 1.1598x; 1.1598x over previous
//
#include <hip/hip_runtime.h>

#define IH 512
#define IW 512
#define OH 510
#define OW 510
#define NB 32
#define KO 16

typedef float f32x4 __attribute__((ext_vector_type(4)));
typedef float f32x2 __attribute__((ext_vector_type(2)));

// Grid = (row-pair x, plane y). Dispatch is x-fastest, so the ~2K resident
// blocks cover ~8 CONSECUTIVE planes = one compact ~8MB sliding write window
// (planes are contiguous in NCHW). Each thread: 6 loads, 36 FMA, ONE float4
// store -> no per-wave multi-plane scatter. Consecutive planes share image n,
// so the 16x logical x re-reads hit L2/L3; HBM fetch stays ~35 MB.
__global__ __launch_bounds__(256) void conv3x3_k16_kernel(
    const float* __restrict__ x,
    const float* __restrict__ k,
    float* __restrict__ out)
{
    const int p  = blockIdx.y;          // plane = n*16 + o
    const int o  = p & 15;
    const int n  = p >> 4;
    const int i0 = blockIdx.x * 2;      // even base row

    const int t    = threadIdx.x;
    const int half = t >> 7;            // 0: even row, 1: odd row
    const int tt   = t & 127;
    const bool tail = (tt == 127);
    const int i    = i0 + half;         // output row

    // Even rows: j = 4*tt (tail j=508). Odd rows: j = 4*tt+2 (tail j=0).
    // Keeps (i*OW + j)*4 % 16 == 0 for all full threads (row stride 2040B).
    int j;
    if ((i & 1) == 0) j = tail ? 508 : 4 * tt;
    else              j = tail ? 0   : 4 * tt + 2;

    // 9 weights, thread-uniform -> SGPRs
    float w[9];
#pragma unroll
    for (int q = 0; q < 9; ++q) w[q] = k[o * 9 + q];

    const float* xr = x + ((size_t)n * IH + i) * IW + j;

    // 3 rows x 6 cols of input (tail: 3 x 4). j even -> 8B-aligned float2.
    float xv[3][6];
#pragma unroll
    for (int rr = 0; rr < 3; ++rr) {
        const float2 a = *reinterpret_cast<const float2*>(xr + rr * IW);
        const float2 b = *reinterpret_cast<const float2*>(xr + rr * IW + 2);
        xv[rr][0] = a.x; xv[rr][1] = a.y; xv[rr][2] = b.x; xv[rr][3] = b.y;
        if (!tail) {
            const float2 c = *reinterpret_cast<const float2*>(xr + rr * IW + 4);
            xv[rr][4] = c.x; xv[rr][5] = c.y;
        } else {
            xv[rr][4] = 0.0f; xv[rr][5] = 0.0f;
        }
    }

    float acc0 = 0.0f, acc1 = 0.0f, acc2 = 0.0f, acc3 = 0.0f;
#pragma unroll
    for (int rr = 0; rr < 3; ++rr) {
#pragma unroll
        for (int c = 0; c < 3; ++c) {
            const float kv = w[rr * 3 + c];
            acc0 = fmaf(xv[rr][c],     kv, acc0);
            acc1 = fmaf(xv[rr][c + 1], kv, acc1);
            acc2 = fmaf(xv[rr][c + 2], kv, acc2);
            acc3 = fmaf(xv[rr][c + 3], kv, acc3);
        }
    }

    float* pout = out + (((size_t)p) * OH + i) * OW + j;
    if (!tail) {
        f32x4 v; v.x = acc0; v.y = acc1; v.z = acc2; v.w = acc3;
        __builtin_nontemporal_store(v, reinterpret_cast<f32x4*>(pout));
    } else {
        f32x2 v; v.x = acc0; v.y = acc1;
        __builtin_nontemporal_store(v, reinterpret_cast<f32x2*>(pout));
    }
}

extern "C" void kernel_launch(void* const* d_in, const int* in_sizes, int n_in,
                              void* d_out, int out_size, void* d_ws, size_t ws_size,
                              hipStream_t stream) {
    const float* x   = (const float*)d_in[0];
    const float* ker = (const float*)d_in[1];
    float* out       = (float*)d_out;

    dim3 grid(OH / 2, NB * KO);   // (255 row-pairs, 512 planes)
    dim3 block(256);
    conv3x3_k16_kernel<<<grid, block, 0, stream>>>(x, ker, out);
}